// Round 1
// baseline (2381.755 us; speedup 1.0000x reference)
//
#include <hip/hip_runtime.h>
#include <math.h>
#include <stdint.h>
#include <stddef.h>

namespace {

constexpr int T = 8;
constexpr int N = 8192;      // nodes (2^13)
constexpr int E = 131072;    // edges (2^17)
constexpr int H = 8;         // heads
constexpr int C = 100;       // communities
constexpr int DG = 128;      // D_GAT
constexpr int DH = 16;       // per-head dim
constexpr int DAGG = 384;    // 3*DG
constexpr int DR = 256;      // D_RNN
constexpr int ZW = 4 * DR;   // 1024

__device__ __forceinline__ float sigmoidf_(float x) { return 1.0f / (1.0f + expf(-x)); }

// ---------------- CSR build (by dst) ----------------
__global__ __launch_bounds__(256) void k_count(const int* __restrict__ ei, int* __restrict__ deg) {
    int gid = blockIdx.x * 256 + threadIdx.x;          // T*E threads
    int t = gid >> 17;
    int e = gid & (E - 1);
    int dst = ei[(size_t)t * 2 * E + E + e];
    atomicAdd(&deg[t * N + dst], 1);
}

__global__ __launch_bounds__(256) void k_scan(const int* __restrict__ deg, int* __restrict__ off) {
    __shared__ int part[256];
    int t = blockIdx.x, tid = threadIdx.x;
    int vals[32];
    int s = 0;
    int base = t * N + tid * 32;
#pragma unroll
    for (int i = 0; i < 32; ++i) { vals[i] = deg[base + i]; s += vals[i]; }
    part[tid] = s;
    __syncthreads();
    if (tid == 0) {
        int run = 0;
        for (int i = 0; i < 256; ++i) { int v = part[i]; part[i] = run; run += v; }
    }
    __syncthreads();
    int run = part[tid];
    int ob = t * (N + 1) + tid * 32;
#pragma unroll
    for (int i = 0; i < 32; ++i) { off[ob + i] = run; run += vals[i]; }
    if (tid == 255) off[t * (N + 1) + N] = run;
}

__global__ __launch_bounds__(256) void k_fill(const int* __restrict__ ei, const float* __restrict__ ew,
                                              const int* __restrict__ off, int* __restrict__ cur,
                                              int* __restrict__ csr_src, float* __restrict__ csr_w) {
    int gid = blockIdx.x * 256 + threadIdx.x;
    int t = gid >> 17;
    int e = gid & (E - 1);
    int src = ei[(size_t)t * 2 * E + e];
    int dst = ei[(size_t)t * 2 * E + E + e];
    int pos = off[t * (N + 1) + dst] + atomicAdd(&cur[t * N + dst], 1);
    csr_src[(size_t)t * E + pos] = src;
    csr_w[(size_t)t * E + pos] = ew[(size_t)t * E + e];
}

// ---------------- generic fp32 GEMM ----------------
// C[M,Nc] = act( bias + A1@B1 (+ A2@B2 if DUAL) ), row-major, K % 16 == 0.
// 128x128 tile, BK=16, 256 threads, 8x8 per thread.  ACT: 0 none, 1 tanh, 2 sigmoid.
template <int ACT, bool DUAL>
__global__ __launch_bounds__(256) void k_gemm(const float* __restrict__ A1, const float* __restrict__ B1, int K1,
                                              const float* __restrict__ A2, const float* __restrict__ B2, int K2,
                                              const float* __restrict__ bias, float* __restrict__ Cmat,
                                              int M, int Nc) {
    __shared__ float As[16][132];   // [k][row], padded, 16B-aligned rows (132*4=528=33*16)
    __shared__ float Bs[16][132];   // [k][col]
    const int tid = threadIdx.x;
    const int tm = tid >> 4, tn = tid & 15;
    const int m0 = blockIdx.y * 128, n0 = blockIdx.x * 128;
    float acc[8][8];
#pragma unroll
    for (int i = 0; i < 8; ++i)
#pragma unroll
        for (int j = 0; j < 8; ++j) acc[i][j] = 0.f;

    const int nphase = DUAL ? 2 : 1;
    for (int ph = 0; ph < nphase; ++ph) {
        const float* __restrict__ A = ph ? A2 : A1;
        const float* __restrict__ B = ph ? B2 : B1;
        const int K = ph ? K2 : K1;
        for (int k0 = 0; k0 < K; k0 += 16) {
#pragma unroll
            for (int it = 0; it < 2; ++it) {
                int f = tid + it * 256;
                // A tile: 128 rows x 16 k
                int r = f >> 2, kq = f & 3;
                float4 v = make_float4(0.f, 0.f, 0.f, 0.f);
                int row = m0 + r;
                if (row < M) v = *(const float4*)(A + (size_t)row * K + k0 + kq * 4);
                As[kq * 4 + 0][r] = v.x;
                As[kq * 4 + 1][r] = v.y;
                As[kq * 4 + 2][r] = v.z;
                As[kq * 4 + 3][r] = v.w;
                // B tile: 16 k x 128 cols
                int kr = f >> 5, c4 = f & 31;
                int col = n0 + c4 * 4;
                float4 w = make_float4(0.f, 0.f, 0.f, 0.f);
                if (col < Nc) w = *(const float4*)(B + (size_t)(k0 + kr) * Nc + col);
                *(float4*)&Bs[kr][c4 * 4] = w;
            }
            __syncthreads();
#pragma unroll
            for (int kk = 0; kk < 16; ++kk) {
                float a[8], b[8];
                *(float4*)&a[0] = *(const float4*)&As[kk][tm * 4];
                *(float4*)&a[4] = *(const float4*)&As[kk][64 + tm * 4];
                *(float4*)&b[0] = *(const float4*)&Bs[kk][tn * 4];
                *(float4*)&b[4] = *(const float4*)&Bs[kk][64 + tn * 4];
#pragma unroll
                for (int i = 0; i < 8; ++i)
#pragma unroll
                    for (int j = 0; j < 8; ++j) acc[i][j] = fmaf(a[i], b[j], acc[i][j]);
            }
            __syncthreads();
        }
    }
#pragma unroll
    for (int i = 0; i < 8; ++i) {
        int row = m0 + ((i < 4) ? (tm * 4 + i) : (64 + tm * 4 + (i - 4)));
        if (row >= M) continue;
#pragma unroll
        for (int jh = 0; jh < 2; ++jh) {
            int col = n0 + ((jh == 0) ? (tn * 4) : (64 + tn * 4));
            if (col >= Nc) continue;
            float v[4];
#pragma unroll
            for (int q = 0; q < 4; ++q) v[q] = acc[i][jh * 4 + q];
            if (bias) {
#pragma unroll
                for (int q = 0; q < 4; ++q) v[q] += bias[col + q];
            }
            if (ACT == 1) {
#pragma unroll
                for (int q = 0; q < 4; ++q) v[q] = tanhf(v[q]);
            } else if (ACT == 2) {
#pragma unroll
                for (int q = 0; q < 4; ++q) v[q] = sigmoidf_(v[q]);
            }
            float4 o;
            o.x = v[0]; o.y = v[1]; o.z = v[2]; o.w = v[3];
            *(float4*)(Cmat + (size_t)row * Nc + col) = o;
        }
    }
}

// ---------------- GAT ----------------
__global__ __launch_bounds__(256) void k_scores(const float* __restrict__ h, const float* __restrict__ asrc,
                                                const float* __restrict__ adst, float* __restrict__ ss,
                                                float* __restrict__ sd) {
    int gid = blockIdx.x * 256 + threadIdx.x;  // (t*N+n)*H + hd
    int hd = gid & 7;
    int node = gid >> 3;
    const float* hr = h + (size_t)node * DG + hd * DH;
    const float* as = asrc + hd * DH;
    const float* ad = adst + hd * DH;
    float s1 = 0.f, s2 = 0.f;
#pragma unroll
    for (int d = 0; d < DH; ++d) { float v = hr[d]; s1 += v * as[d]; s2 += v * ad[d]; }
    ss[gid] = s1;
    sd[gid] = s2;
}

// one thread per (node, head): online softmax over incoming edges (CSR), elu epilogue
__global__ __launch_bounds__(256) void k_gat_agg(const float* __restrict__ h, const float* __restrict__ ss,
                                                 const float* __restrict__ sd, const int* __restrict__ csr_src,
                                                 const float* __restrict__ csr_w, const int* __restrict__ off,
                                                 float* __restrict__ outp) {
    int tid = threadIdx.x;
    int hd = tid & 7, nl = tid >> 3;   // 32 nodes x 8 heads per block
    int t = blockIdx.y;
    int n = blockIdx.x * 32 + nl;
    int p0 = off[t * (N + 1) + n], p1 = off[t * (N + 1) + n + 1];
    const int* cs = csr_src + (size_t)t * E;
    const float* cw = csr_w + (size_t)t * E;
    const float* st = ss + (size_t)t * N * H;
    const float* ht = h + (size_t)t * N * DG;
    float sdv = sd[((size_t)t * N + n) * H + hd];
    float m = -INFINITY, l = 0.f;
    float acc[16];
#pragma unroll
    for (int d = 0; d < 16; ++d) acc[d] = 0.f;
    for (int p = p0; p < p1; ++p) {
        int src = cs[p];
        float w = cw[p];
        float e = st[src * H + hd] + sdv;
        e = (e >= 0.f) ? e : 0.2f * e;   // leaky_relu(., 0.2)
        e *= w;
        float mn = fmaxf(m, e);
        float sc = expf(m - mn);         // exp(-inf)=0 handles first iter
        float pr = expf(e - mn);
        l = l * sc + pr;
        const float4* hv = (const float4*)(ht + (size_t)src * DG + hd * DH);
        float4 q0 = hv[0], q1 = hv[1], q2 = hv[2], q3 = hv[3];
        float hvv[16] = {q0.x, q0.y, q0.z, q0.w, q1.x, q1.y, q1.z, q1.w,
                         q2.x, q2.y, q2.z, q2.w, q3.x, q3.y, q3.z, q3.w};
#pragma unroll
        for (int d = 0; d < 16; ++d) acc[d] = acc[d] * sc + pr * hvv[d];
        m = mn;
    }
    float inv = 1.f / (l + 1e-16f);
    float* op = outp + ((size_t)t * N + n) * DG + hd * DH;
#pragma unroll
    for (int d = 0; d < 16; ++d) {
        float v = acc[d] * inv;
        v = (v > 0.f) ? v : (expf(v) - 1.f);  // elu
        op[d] = v;
    }
}

// ---------------- fuse (micro/meso/macro) ----------------
__global__ __launch_bounds__(256) void k_fuse_scatter(const float* __restrict__ x, const int* __restrict__ com,
                                                      const float* __restrict__ nw, float* __restrict__ num,
                                                      float* __restrict__ den) {
    int gid = blockIdx.x * 256 + threadIdx.x;  // T*N*DG
    int d = gid & 127;
    int node = gid >> 7;                        // t*N+n
    int t = node >> 13;
    int c = com[node];
    float w = nw[node];
    atomicAdd(&num[((size_t)t * C + c) * DG + d], w * x[gid]);
    if (d == 0) atomicAdd(&den[t * C + c], w);
}

__global__ void k_fuse_macro(const float* __restrict__ num, const float* __restrict__ den, float* __restrict__ mac) {
    int gid = blockIdx.x * 256 + threadIdx.x;  // T*DG
    if (gid >= T * DG) return;
    int t = gid >> 7, d = gid & 127;
    float s = 0.f, ws = 0.f;
    for (int c = 0; c < C; ++c) { s += num[((size_t)t * C + c) * DG + d]; ws += den[t * C + c]; }
    mac[gid] = s / (ws + 1e-16f);  // macro = sum_n w*x / (sum w + eps)
}

__global__ __launch_bounds__(256) void k_fuse_alpha(const float* __restrict__ x, const int* __restrict__ com,
                                                    const float* __restrict__ num, const float* __restrict__ den,
                                                    const float* __restrict__ mac, float* __restrict__ alpha) {
    int node = blockIdx.x * 256 + threadIdx.x;  // t*N+n
    int t = node >> 13;
    int c = com[node];
    const float* xr = x + (size_t)node * DG;
    const float* nr = num + ((size_t)t * C + c) * DG;
    const float* mr = mac + t * DG;
    float dn = den[t * C + c] + 1e-16f;
    float s0 = 0.f, s1 = 0.f, s2 = 0.f;
    for (int d = 0; d < DG; d += 4) {
        float4 a = *(const float4*)(xr + d);
        float4 b = *(const float4*)(nr + d);
        float4 g = *(const float4*)(mr + d);
        s0 += a.x + a.y + a.z + a.w;
        s1 += b.x + b.y + b.z + b.w;
        s2 += g.x + g.y + g.z + g.w;
    }
    s0 *= (1.f / DG);
    s1 = (s1 / dn) * (1.f / DG);
    s2 *= (1.f / DG);
    s0 = (s0 >= 0.f) ? s0 : 0.2f * s0;
    s1 = (s1 >= 0.f) ? s1 : 0.2f * s1;
    s2 = (s2 >= 0.f) ? s2 : 0.2f * s2;
    float mx = fmaxf(s0, fmaxf(s1, s2));
    float e0 = expf(s0 - mx), e1 = expf(s1 - mx), e2 = expf(s2 - mx);
    float inv = 1.f / (e0 + e1 + e2);
    alpha[(size_t)node * 3 + 0] = e0 * inv;
    alpha[(size_t)node * 3 + 1] = e1 * inv;
    alpha[(size_t)node * 3 + 2] = e2 * inv;
}

__global__ __launch_bounds__(256) void k_fuse_agg(const float* __restrict__ x, const int* __restrict__ com,
                                                  const float* __restrict__ num, const float* __restrict__ den,
                                                  const float* __restrict__ mac, const float* __restrict__ alpha,
                                                  float* __restrict__ agg) {
    int gid = blockIdx.x * 256 + threadIdx.x;  // T*N*DG
    int d = gid & 127;
    int node = gid >> 7;
    int t = node >> 13;
    int c = com[node];
    float a0 = alpha[(size_t)node * 3 + 0];
    float a1 = alpha[(size_t)node * 3 + 1];
    float a2 = alpha[(size_t)node * 3 + 2];
    float xv = x[gid];
    float mes = num[((size_t)t * C + c) * DG + d] / (den[t * C + c] + 1e-16f);
    float mv = mac[t * DG + d];
    float* o = agg + (size_t)node * DAGG;
    o[d] = a0 * xv;
    o[DG + d] = a1 * mes;
    o[2 * DG + d] = a2 * mv;
}

// ---------------- LSTM gates ----------------
__global__ __launch_bounds__(256) void k_gates(const float* __restrict__ z, float* __restrict__ c,
                                               float* __restrict__ h) {
    int gid = blockIdx.x * 256 + threadIdx.x;  // N*DR
    int n = gid >> 8, j = gid & 255;
    const float* zr = z + (size_t)n * ZW;
    float iv = sigmoidf_(zr[j]);
    float fv = sigmoidf_(zr[DR + j]);
    float gv = tanhf(zr[2 * DR + j]);
    float ov = sigmoidf_(zr[3 * DR + j]);
    float cn = fv * c[gid] + iv * gv;
    float hn = ov * tanhf(cn);
    c[gid] = cn;
    h[gid] = hn;
}

// ---------------- embedding normalization ----------------
__global__ __launch_bounds__(256) void k_colsum(const float* __restrict__ emb, float* __restrict__ cs) {
    __shared__ float part[4][64];
    int tid = threadIdx.x;
    int d = tid & 63, rg = tid >> 6;
    int r0 = blockIdx.x * 64;
    float s = 0.f;
    for (int r = rg; r < 64; r += 4) { float v = emb[(size_t)(r0 + r) * 64 + d]; s += v * v; }
    part[rg][d] = s;
    __syncthreads();
    if (tid < 64) atomicAdd(&cs[tid], part[0][tid] + part[1][tid] + part[2][tid] + part[3][tid]);
}

__global__ __launch_bounds__(256) void k_embn(const float* __restrict__ emb, const float* __restrict__ cs,
                                              float* __restrict__ en) {
    int gid = blockIdx.x * 256 + threadIdx.x;  // N*64
    float nrm = fmaxf(sqrtf(cs[gid & 63]), 1e-12f);
    en[gid] = emb[gid] / nrm;
}

__global__ __launch_bounds__(256) void k_sq(const float* __restrict__ en, float* __restrict__ sqv) {
    int n = blockIdx.x * 256 + threadIdx.x;
    const float4* r = (const float4*)(en + (size_t)n * 64);
    float s = 0.f;
#pragma unroll
    for (int q = 0; q < 16; ++q) { float4 v = r[q]; s += v.x * v.x + v.y * v.y + v.z * v.z + v.w * v.w; }
    sqv[n] = s;
}

// ---------------- fused adjacency: 1 + tanh(-(sq_i+sq_j-2*G_ij)*S_ij) ----------------
__global__ __launch_bounds__(256) void k_adj(const float* __restrict__ en, const float* __restrict__ sc,
                                             const float* __restrict__ sqv, float* __restrict__ outp) {
    __shared__ float Ti[32][68], Tj[32][68], Si[32][68], Sj[32][68];  // [k][row]
    __shared__ float sqi[64], sqj[64];
    int tid = threadIdx.x;
    int i0 = blockIdx.y * 64, j0 = blockIdx.x * 64;
    if (tid < 64) sqi[tid] = sqv[i0 + tid];
    else if (tid < 128) sqj[tid - 64] = sqv[j0 + tid - 64];
    float accg[4][4] = {{0.f}}, accs[4][4] = {{0.f}};
    int tm = tid >> 4, tn = tid & 15;
    for (int k0 = 0; k0 < 64; k0 += 32) {
        __syncthreads();
#pragma unroll
        for (int it = 0; it < 2; ++it) {
            int f = tid + it * 256;
            int r = f >> 3, kq = f & 7;
            float4 v;
            v = *(const float4*)(en + (size_t)(i0 + r) * 64 + k0 + kq * 4);
            Ti[kq * 4 + 0][r] = v.x; Ti[kq * 4 + 1][r] = v.y; Ti[kq * 4 + 2][r] = v.z; Ti[kq * 4 + 3][r] = v.w;
            v = *(const float4*)(en + (size_t)(j0 + r) * 64 + k0 + kq * 4);
            Tj[kq * 4 + 0][r] = v.x; Tj[kq * 4 + 1][r] = v.y; Tj[kq * 4 + 2][r] = v.z; Tj[kq * 4 + 3][r] = v.w;
            v = *(const float4*)(sc + (size_t)(i0 + r) * 64 + k0 + kq * 4);
            Si[kq * 4 + 0][r] = v.x; Si[kq * 4 + 1][r] = v.y; Si[kq * 4 + 2][r] = v.z; Si[kq * 4 + 3][r] = v.w;
            v = *(const float4*)(sc + (size_t)(j0 + r) * 64 + k0 + kq * 4);
            Sj[kq * 4 + 0][r] = v.x; Sj[kq * 4 + 1][r] = v.y; Sj[kq * 4 + 2][r] = v.z; Sj[kq * 4 + 3][r] = v.w;
        }
        __syncthreads();
#pragma unroll
        for (int kk = 0; kk < 32; ++kk) {
            float4 ag = *(const float4*)&Ti[kk][tm * 4];
            float4 bg = *(const float4*)&Tj[kk][tn * 4];
            float4 as = *(const float4*)&Si[kk][tm * 4];
            float4 bs = *(const float4*)&Sj[kk][tn * 4];
            float a[4] = {ag.x, ag.y, ag.z, ag.w};
            float b[4] = {bg.x, bg.y, bg.z, bg.w};
            float c2[4] = {as.x, as.y, as.z, as.w};
            float d2[4] = {bs.x, bs.y, bs.z, bs.w};
#pragma unroll
            for (int i = 0; i < 4; ++i)
#pragma unroll
                for (int j = 0; j < 4; ++j) {
                    accg[i][j] = fmaf(a[i], b[j], accg[i][j]);
                    accs[i][j] = fmaf(c2[i], d2[j], accs[i][j]);
                }
        }
    }
#pragma unroll
    for (int mi = 0; mi < 4; ++mi) {
        int i = i0 + tm * 4 + mi;
        float si = sqi[tm * 4 + mi];
        float4 v;
        v.x = 1.f + tanhf(-(si + sqj[tn * 4 + 0] - 2.f * accg[mi][0]) * accs[mi][0]);
        v.y = 1.f + tanhf(-(si + sqj[tn * 4 + 1] - 2.f * accg[mi][1]) * accs[mi][1]);
        v.z = 1.f + tanhf(-(si + sqj[tn * 4 + 2] - 2.f * accg[mi][2]) * accs[mi][2]);
        v.w = 1.f + tanhf(-(si + sqj[tn * 4 + 3] - 2.f * accg[mi][3]) * accs[mi][3]);
        *(float4*)(outp + (size_t)i * N + j0 + tn * 4) = v;
    }
}

}  // namespace

extern "C" void kernel_launch(void* const* d_in, const int* in_sizes, int n_in,
                              void* d_out, int out_size, void* d_ws, size_t ws_size,
                              hipStream_t stream) {
    const int* ei = (const int*)d_in[0];
    const float* ew = (const float*)d_in[1];
    const float* feat = (const float*)d_in[2];
    const int* com = (const int*)d_in[3];
    const float* nw = (const float*)d_in[4];
    const float* gat_W = (const float*)d_in[5];
    const float* gat_asrc = (const float*)d_in[6];
    const float* gat_adst = (const float*)d_in[7];
    const float* lstm_Wx = (const float*)d_in[8];
    const float* lstm_Wh = (const float*)d_in[9];
    const float* lstm_b = (const float*)d_in[10];
    const float* emb_W0 = (const float*)d_in[11];
    const float* emb_b0 = (const float*)d_in[12];
    const float* emb_W1 = (const float*)d_in[13];
    const float* emb_b1 = (const float*)d_in[14];
    const float* scal_W0 = (const float*)d_in[15];
    const float* scal_b0 = (const float*)d_in[16];
    const float* scal_W1 = (const float*)d_in[17];
    const float* scal_b1 = (const float*)d_in[18];
    float* out = (float*)d_out;

    char* wp = (char*)d_ws;
    auto alloc = [&](size_t bytes) -> void* {
        void* p = (void*)wp;
        wp += (bytes + 255) & ~(size_t)255;
        return p;
    };
    int* csr_src = (int*)alloc((size_t)T * E * 4);
    float* csr_wf = (float*)alloc((size_t)T * E * 4);
    int* csr_off = (int*)alloc((size_t)T * (N + 1) * 4);
    int* deg = (int*)alloc((size_t)T * N * 4);
    float* bufA = (float*)alloc((size_t)T * N * DG * 4);
    float* bufB = (float*)alloc((size_t)T * N * DG * 4);
    float* ssrc = (float*)alloc((size_t)T * N * H * 4);
    float* sdst = (float*)alloc((size_t)T * N * H * 4);
    float* numb = (float*)alloc((size_t)T * C * DG * 4);
    float* denb = (float*)alloc((size_t)T * C * 4);
    float* macv = (float*)alloc((size_t)T * DG * 4);
    float* alph = (float*)alloc((size_t)T * N * 3 * 4);
    float* agg = (float*)alloc((size_t)T * N * DAGG * 4);
    float* zbuf = (float*)alloc((size_t)N * ZW * 4);
    float* hbuf = (float*)alloc((size_t)N * DR * 4);
    float* cbuf = (float*)alloc((size_t)N * DR * 4);
    float* e1b = (float*)alloc((size_t)N * 128 * 4);
    float* s1b = (float*)alloc((size_t)N * 128 * 4);
    float* embb = (float*)alloc((size_t)N * 64 * 4);
    float* sclb = (float*)alloc((size_t)N * 64 * 4);
    float* embnb = (float*)alloc((size_t)N * 64 * 4);
    float* cols = (float*)alloc(64 * 4);
    float* sqb = (float*)alloc((size_t)N * 4);

    // ---- CSR by dst (shared by both GAT layers) ----
    hipMemsetAsync(deg, 0, (size_t)T * N * 4, stream);
    k_count<<<(T * E) / 256, 256, 0, stream>>>(ei, deg);
    k_scan<<<T, 256, 0, stream>>>(deg, csr_off);
    hipMemsetAsync(deg, 0, (size_t)T * N * 4, stream);
    k_fill<<<(T * E) / 256, 256, 0, stream>>>(ei, ew, csr_off, deg, csr_src, csr_wf);

    // ---- GAT layer 0: feat -> bufB ----
    k_gemm<0, false><<<dim3(1, (T * N) / 128), 256, 0, stream>>>(feat, gat_W, DG, nullptr, nullptr, 0, nullptr,
                                                                 bufA, T * N, DG);
    k_scores<<<(T * N * H) / 256, 256, 0, stream>>>(bufA, gat_asrc, gat_adst, ssrc, sdst);
    k_gat_agg<<<dim3(N / 32, T), 256, 0, stream>>>(bufA, ssrc, sdst, csr_src, csr_wf, csr_off, bufB);
    // ---- GAT layer 1: bufB -> bufB ----
    k_gemm<0, false><<<dim3(1, (T * N) / 128), 256, 0, stream>>>(bufB, gat_W + DG * DG, DG, nullptr, nullptr, 0,
                                                                 nullptr, bufA, T * N, DG);
    k_scores<<<(T * N * H) / 256, 256, 0, stream>>>(bufA, gat_asrc + H * DH, gat_adst + H * DH, ssrc, sdst);
    k_gat_agg<<<dim3(N / 32, T), 256, 0, stream>>>(bufA, ssrc, sdst, csr_src, csr_wf, csr_off, bufB);

    // ---- fuse to agg [T,N,384] ----
    hipMemsetAsync(numb, 0, (size_t)T * C * DG * 4, stream);
    hipMemsetAsync(denb, 0, (size_t)T * C * 4, stream);
    k_fuse_scatter<<<(T * N * DG) / 256, 256, 0, stream>>>(bufB, com, nw, numb, denb);
    k_fuse_macro<<<(T * DG + 255) / 256, 256, 0, stream>>>(numb, denb, macv);
    k_fuse_alpha<<<(T * N) / 256, 256, 0, stream>>>(bufB, com, numb, denb, macv, alph);
    k_fuse_agg<<<(T * N * DG) / 256, 256, 0, stream>>>(bufB, com, numb, denb, macv, alph, agg);

    // ---- LSTM over T steps ----
    hipMemsetAsync(hbuf, 0, (size_t)N * DR * 4, stream);
    hipMemsetAsync(cbuf, 0, (size_t)N * DR * 4, stream);
    for (int t = 0; t < T; ++t) {
        k_gemm<0, true><<<dim3(ZW / 128, N / 128), 256, 0, stream>>>(agg + (size_t)t * N * DAGG, lstm_Wx, DAGG,
                                                                     hbuf, lstm_Wh, DR, lstm_b, zbuf, N, ZW);
        k_gates<<<(N * DR) / 256, 256, 0, stream>>>(zbuf, cbuf, hbuf);
    }

    // ---- decoders ----
    k_gemm<1, false><<<dim3(1, N / 128), 256, 0, stream>>>(hbuf, emb_W0, DR, nullptr, nullptr, 0, emb_b0, e1b, N, 128);
    k_gemm<1, false><<<dim3(1, N / 128), 256, 0, stream>>>(e1b, emb_W1, 128, nullptr, nullptr, 0, emb_b1, embb, N, 64);
    k_gemm<2, false><<<dim3(1, N / 128), 256, 0, stream>>>(hbuf, scal_W0, DR, nullptr, nullptr, 0, scal_b0, s1b, N, 128);
    k_gemm<2, false><<<dim3(1, N / 128), 256, 0, stream>>>(s1b, scal_W1, 128, nullptr, nullptr, 0, scal_b1, sclb, N, 64);

    // emb goes to output tail
    hipMemcpyAsync(out + (size_t)N * N, embb, (size_t)N * 64 * 4, hipMemcpyDeviceToDevice, stream);

    // ---- normalize + pairwise adjacency ----
    hipMemsetAsync(cols, 0, 64 * 4, stream);
    k_colsum<<<N / 64, 256, 0, stream>>>(embb, cols);
    k_embn<<<(N * 64) / 256, 256, 0, stream>>>(embb, cols, embnb);
    k_sq<<<N / 256, 256, 0, stream>>>(embnb, sqb);
    k_adj<<<dim3(N / 64, N / 64), 256, 0, stream>>>(embnb, sclb, sqb, out);
}

// Round 2
// 1262.160 us; speedup vs baseline: 1.8870x; 1.8870x over previous
//
#include <hip/hip_runtime.h>
#include <math.h>
#include <stdint.h>
#include <stddef.h>

namespace {

constexpr int T = 8;
constexpr int N = 8192;      // nodes (2^13)
constexpr int E = 131072;    // edges (2^17)
constexpr int H = 8;         // heads
constexpr int C = 100;       // communities
constexpr int DG = 128;      // D_GAT
constexpr int DH = 16;       // per-head dim
constexpr int DAGG = 384;    // 3*DG
constexpr int DR = 256;      // D_RNN
constexpr int ZW = 4 * DR;   // 1024

typedef __bf16 bf16x8 __attribute__((ext_vector_type(8)));
typedef float f32x4 __attribute__((ext_vector_type(4)));

__device__ __forceinline__ float sigmoidf_(float x) { return 1.0f / (1.0f + expf(-x)); }

__device__ __forceinline__ unsigned short f2b(float f) {
    union { float f; uint32_t u; } v; v.f = f;
    uint32_t r = v.u + 0x7fffu + ((v.u >> 16) & 1u);
    return (unsigned short)(r >> 16);
}
__device__ __forceinline__ float b2f(unsigned short u) {
    union { uint32_t u; float f; } v; v.u = ((uint32_t)u) << 16;
    return v.f;
}

// ---------------- CSR build (by dst) ----------------
__global__ __launch_bounds__(256) void k_count(const int* __restrict__ ei, int* __restrict__ deg) {
    int gid = blockIdx.x * 256 + threadIdx.x;          // T*E threads
    int t = gid >> 17;
    int e = gid & (E - 1);
    int dst = ei[(size_t)t * 2 * E + E + e];
    atomicAdd(&deg[t * N + dst], 1);
}

__global__ __launch_bounds__(256) void k_scan(const int* __restrict__ deg, int* __restrict__ off) {
    __shared__ int part[256];
    int t = blockIdx.x, tid = threadIdx.x;
    int vals[32];
    int s = 0;
    int base = t * N + tid * 32;
#pragma unroll
    for (int i = 0; i < 32; ++i) { vals[i] = deg[base + i]; s += vals[i]; }
    part[tid] = s;
    __syncthreads();
    if (tid == 0) {
        int run = 0;
        for (int i = 0; i < 256; ++i) { int v = part[i]; part[i] = run; run += v; }
    }
    __syncthreads();
    int run = part[tid];
    int ob = t * (N + 1) + tid * 32;
#pragma unroll
    for (int i = 0; i < 32; ++i) { off[ob + i] = run; run += vals[i]; }
    if (tid == 255) off[t * (N + 1) + N] = run;
}

__global__ __launch_bounds__(256) void k_fill(const int* __restrict__ ei, const float* __restrict__ ew,
                                              const int* __restrict__ off, int* __restrict__ cur,
                                              int* __restrict__ csr_src, float* __restrict__ csr_w) {
    int gid = blockIdx.x * 256 + threadIdx.x;
    int t = gid >> 17;
    int e = gid & (E - 1);
    int src = ei[(size_t)t * 2 * E + e];
    int dst = ei[(size_t)t * 2 * E + E + e];
    int pos = off[t * (N + 1) + dst] + atomicAdd(&cur[t * N + dst], 1);
    csr_src[(size_t)t * E + pos] = src;
    csr_w[(size_t)t * E + pos] = ew[(size_t)t * E + e];
}

// ---------------- fp32 -> bf16 elementwise ----------------
__global__ __launch_bounds__(256) void k_f2bv(const float* __restrict__ x, unsigned short* __restrict__ y) {
    int gid = blockIdx.x * 256 + threadIdx.x;
    y[gid] = f2b(x[gid]);
}

// ---------------- weight transpose + bf16: B[K][Nc] -> BT[Npad][K] ----------------
__global__ __launch_bounds__(64) void k_wtrans(const float* __restrict__ B, unsigned short* __restrict__ BT,
                                               int K, int Nc) {
    int n = blockIdx.y;
    int k = blockIdx.x * 64 + threadIdx.x;
    BT[(size_t)n * K + k] = (n < Nc) ? f2b(B[(size_t)k * Nc + n]) : (unsigned short)0;
}

// ---------------- bf16 MFMA GEMM:  C = act(bias + A1@B1T^T (+ A2@B2T^T)) ----------------
// A [M,K] bf16 row-major, BT [Nc_pad,K] bf16 (i.e. B^T), C row-major [M,Nc].
// 128x128 tile, BK=32, 256 threads = 4 waves of 64x64, 16x16x32 MFMA.
// M % 128 == 0, K % 32 == 0, BT padded to >=128 rows per tile. ACT: 0 none, 1 tanh, 2 sigmoid.
template <int ACT, int NPH, bool BF16OUT>
__global__ __launch_bounds__(256) void k_mgemm(const unsigned short* __restrict__ A1,
                                               const unsigned short* __restrict__ B1T, int K1,
                                               const unsigned short* __restrict__ A2,
                                               const unsigned short* __restrict__ B2T, int K2,
                                               const float* __restrict__ bias, void* __restrict__ Cout,
                                               int M, int Nc) {
    __shared__ unsigned short As[128 * 40];   // rows padded 32->40 (80B) to kill b128 bank conflicts
    __shared__ unsigned short Bs[128 * 40];
    const int tid = threadIdx.x;
    const int m0 = blockIdx.y * 128, n0 = blockIdx.x * 128;
    const int w = tid >> 6, L = tid & 63;
    const int wm = w >> 1, wn = w & 1;
    const int lm = L & 15, koff = (L >> 4) * 8;
    const f32x4 zero = {0.f, 0.f, 0.f, 0.f};
    f32x4 acc[4][4];
#pragma unroll
    for (int i = 0; i < 4; ++i)
#pragma unroll
        for (int j = 0; j < 4; ++j) acc[i][j] = zero;

#pragma unroll
    for (int ph = 0; ph < NPH; ++ph) {
        const unsigned short* __restrict__ A = ph ? A2 : A1;
        const unsigned short* __restrict__ BT = ph ? B2T : B1T;
        const int K = ph ? K2 : K1;
        for (int k0 = 0; k0 < K; k0 += 32) {
#pragma unroll
            for (int it = 0; it < 2; ++it) {
                int f = tid + it * 256;
                int r = f >> 2, q = f & 3;
                *(bf16x8*)&As[r * 40 + q * 8] = *(const bf16x8*)(A + (size_t)(m0 + r) * K + k0 + q * 8);
                *(bf16x8*)&Bs[r * 40 + q * 8] = *(const bf16x8*)(BT + (size_t)(n0 + r) * K + k0 + q * 8);
            }
            __syncthreads();
            bf16x8 af[4], bg[4];
#pragma unroll
            for (int i = 0; i < 4; ++i) af[i] = *(const bf16x8*)&As[(wm * 64 + i * 16 + lm) * 40 + koff];
#pragma unroll
            for (int j = 0; j < 4; ++j) bg[j] = *(const bf16x8*)&Bs[(wn * 64 + j * 16 + lm) * 40 + koff];
#pragma unroll
            for (int i = 0; i < 4; ++i)
#pragma unroll
                for (int j = 0; j < 4; ++j)
                    acc[i][j] = __builtin_amdgcn_mfma_f32_16x16x32_bf16(af[i], bg[j], acc[i][j], 0, 0, 0);
            __syncthreads();
        }
    }

#pragma unroll
    for (int j = 0; j < 4; ++j) {
        int col = n0 + wn * 64 + j * 16 + lm;
        if (col >= Nc) continue;
        float bv = bias ? bias[col] : 0.f;
#pragma unroll
        for (int i = 0; i < 4; ++i) {
            int rb = m0 + wm * 64 + i * 16 + (L >> 4) * 4;
#pragma unroll
            for (int r = 0; r < 4; ++r) {
                float v = acc[i][j][r] + bv;
                if (ACT == 1) v = tanhf(v);
                else if (ACT == 2) v = sigmoidf_(v);
                if (BF16OUT) ((unsigned short*)Cout)[(size_t)(rb + r) * Nc + col] = f2b(v);
                else ((float*)Cout)[(size_t)(rb + r) * Nc + col] = v;
            }
        }
    }
}

// ---------------- GAT ----------------
__global__ __launch_bounds__(256) void k_scores(const float* __restrict__ h, const float* __restrict__ asrc,
                                                const float* __restrict__ adst, float* __restrict__ ss,
                                                float* __restrict__ sd) {
    int gid = blockIdx.x * 256 + threadIdx.x;  // (t*N+n)*H + hd
    int hd = gid & 7;
    int node = gid >> 3;
    const float* hr = h + (size_t)node * DG + hd * DH;
    const float* as = asrc + hd * DH;
    const float* ad = adst + hd * DH;
    float s1 = 0.f, s2 = 0.f;
#pragma unroll
    for (int d = 0; d < DH; ++d) { float v = hr[d]; s1 += v * as[d]; s2 += v * ad[d]; }
    ss[gid] = s1;
    sd[gid] = s2;
}

// one thread per (node, head): online softmax over incoming edges (CSR), elu epilogue
template <bool BF16OUT>
__global__ __launch_bounds__(256) void k_gat_agg(const float* __restrict__ h, const float* __restrict__ ss,
                                                 const float* __restrict__ sd, const int* __restrict__ csr_src,
                                                 const float* __restrict__ csr_w, const int* __restrict__ off,
                                                 void* __restrict__ outp) {
    int tid = threadIdx.x;
    int hd = tid & 7, nl = tid >> 3;   // 32 nodes x 8 heads per block
    int t = blockIdx.y;
    int n = blockIdx.x * 32 + nl;
    int p0 = off[t * (N + 1) + n], p1 = off[t * (N + 1) + n + 1];
    const int* cs = csr_src + (size_t)t * E;
    const float* cw = csr_w + (size_t)t * E;
    const float* st = ss + (size_t)t * N * H;
    const float* ht = h + (size_t)t * N * DG;
    float sdv = sd[((size_t)t * N + n) * H + hd];
    float m = -INFINITY, l = 0.f;
    float acc[16];
#pragma unroll
    for (int d = 0; d < 16; ++d) acc[d] = 0.f;
    for (int p = p0; p < p1; ++p) {
        int src = cs[p];
        float w = cw[p];
        float e = st[src * H + hd] + sdv;
        e = (e >= 0.f) ? e : 0.2f * e;   // leaky_relu(., 0.2)
        e *= w;
        float mn = fmaxf(m, e);
        float sc = expf(m - mn);         // exp(-inf)=0 handles first iter
        float pr = expf(e - mn);
        l = l * sc + pr;
        const float4* hv = (const float4*)(ht + (size_t)src * DG + hd * DH);
        float4 q0 = hv[0], q1 = hv[1], q2 = hv[2], q3 = hv[3];
        float hvv[16] = {q0.x, q0.y, q0.z, q0.w, q1.x, q1.y, q1.z, q1.w,
                         q2.x, q2.y, q2.z, q2.w, q3.x, q3.y, q3.z, q3.w};
#pragma unroll
        for (int d = 0; d < 16; ++d) acc[d] = acc[d] * sc + pr * hvv[d];
        m = mn;
    }
    float inv = 1.f / (l + 1e-16f);
    size_t ob = ((size_t)t * N + n) * DG + hd * DH;
#pragma unroll
    for (int d = 0; d < 16; ++d) {
        float v = acc[d] * inv;
        v = (v > 0.f) ? v : (expf(v) - 1.f);  // elu
        if (BF16OUT) ((unsigned short*)outp)[ob + d] = f2b(v);
        else ((float*)outp)[ob + d] = v;
    }
}

// ---------------- fuse (micro/meso/macro) ----------------
__global__ __launch_bounds__(256) void k_fuse_scatter(const float* __restrict__ x, const int* __restrict__ com,
                                                      const float* __restrict__ nw, float* __restrict__ num,
                                                      float* __restrict__ den) {
    int gid = blockIdx.x * 256 + threadIdx.x;  // T*N*DG
    int d = gid & 127;
    int node = gid >> 7;                        // t*N+n
    int t = node >> 13;
    int c = com[node];
    float w = nw[node];
    atomicAdd(&num[((size_t)t * C + c) * DG + d], w * x[gid]);
    if (d == 0) atomicAdd(&den[t * C + c], w);
}

__global__ void k_fuse_macro(const float* __restrict__ num, const float* __restrict__ den, float* __restrict__ mac) {
    int gid = blockIdx.x * 256 + threadIdx.x;  // T*DG
    if (gid >= T * DG) return;
    int t = gid >> 7, d = gid & 127;
    float s = 0.f, ws = 0.f;
    for (int c = 0; c < C; ++c) { s += num[((size_t)t * C + c) * DG + d]; ws += den[t * C + c]; }
    mac[gid] = s / (ws + 1e-16f);  // macro = sum_n w*x / (sum w + eps)
}

__global__ __launch_bounds__(256) void k_fuse_alpha(const float* __restrict__ x, const int* __restrict__ com,
                                                    const float* __restrict__ num, const float* __restrict__ den,
                                                    const float* __restrict__ mac, float* __restrict__ alpha) {
    int node = blockIdx.x * 256 + threadIdx.x;  // t*N+n
    int t = node >> 13;
    int c = com[node];
    const float* xr = x + (size_t)node * DG;
    const float* nr = num + ((size_t)t * C + c) * DG;
    const float* mr = mac + t * DG;
    float dn = den[t * C + c] + 1e-16f;
    float s0 = 0.f, s1 = 0.f, s2 = 0.f;
    for (int d = 0; d < DG; d += 4) {
        float4 a = *(const float4*)(xr + d);
        float4 b = *(const float4*)(nr + d);
        float4 g = *(const float4*)(mr + d);
        s0 += a.x + a.y + a.z + a.w;
        s1 += b.x + b.y + b.z + b.w;
        s2 += g.x + g.y + g.z + g.w;
    }
    s0 *= (1.f / DG);
    s1 = (s1 / dn) * (1.f / DG);
    s2 *= (1.f / DG);
    s0 = (s0 >= 0.f) ? s0 : 0.2f * s0;
    s1 = (s1 >= 0.f) ? s1 : 0.2f * s1;
    s2 = (s2 >= 0.f) ? s2 : 0.2f * s2;
    float mx = fmaxf(s0, fmaxf(s1, s2));
    float e0 = expf(s0 - mx), e1 = expf(s1 - mx), e2 = expf(s2 - mx);
    float inv = 1.f / (e0 + e1 + e2);
    alpha[(size_t)node * 3 + 0] = e0 * inv;
    alpha[(size_t)node * 3 + 1] = e1 * inv;
    alpha[(size_t)node * 3 + 2] = e2 * inv;
}

__global__ __launch_bounds__(256) void k_fuse_agg(const float* __restrict__ x, const int* __restrict__ com,
                                                  const float* __restrict__ num, const float* __restrict__ den,
                                                  const float* __restrict__ mac, const float* __restrict__ alpha,
                                                  unsigned short* __restrict__ agg) {
    int gid = blockIdx.x * 256 + threadIdx.x;  // T*N*DG
    int d = gid & 127;
    int node = gid >> 7;
    int t = node >> 13;
    int c = com[node];
    float a0 = alpha[(size_t)node * 3 + 0];
    float a1 = alpha[(size_t)node * 3 + 1];
    float a2 = alpha[(size_t)node * 3 + 2];
    float xv = x[gid];
    float mes = num[((size_t)t * C + c) * DG + d] / (den[t * C + c] + 1e-16f);
    float mv = mac[t * DG + d];
    unsigned short* o = agg + (size_t)node * DAGG;
    o[d] = f2b(a0 * xv);
    o[DG + d] = f2b(a1 * mes);
    o[2 * DG + d] = f2b(a2 * mv);
}

// ---------------- LSTM gates ----------------
__global__ __launch_bounds__(256) void k_gates(const float* __restrict__ z, float* __restrict__ c,
                                               unsigned short* __restrict__ h) {
    int gid = blockIdx.x * 256 + threadIdx.x;  // N*DR
    int n = gid >> 8, j = gid & 255;
    const float* zr = z + (size_t)n * ZW;
    float iv = sigmoidf_(zr[j]);
    float fv = sigmoidf_(zr[DR + j]);
    float gv = tanhf(zr[2 * DR + j]);
    float ov = sigmoidf_(zr[3 * DR + j]);
    float cn = fv * c[gid] + iv * gv;
    c[gid] = cn;
    h[gid] = f2b(ov * tanhf(cn));
}

// ---------------- embedding normalization ----------------
__global__ __launch_bounds__(256) void k_colsum(const float* __restrict__ emb, float* __restrict__ cs) {
    __shared__ float part[4][64];
    int tid = threadIdx.x;
    int d = tid & 63, rg = tid >> 6;
    int r0 = blockIdx.x * 64;
    float s = 0.f;
    for (int r = rg; r < 64; r += 4) { float v = emb[(size_t)(r0 + r) * 64 + d]; s += v * v; }
    part[rg][d] = s;
    __syncthreads();
    if (tid < 64) atomicAdd(&cs[tid], part[0][tid] + part[1][tid] + part[2][tid] + part[3][tid]);
}

__global__ __launch_bounds__(256) void k_embn(const float* __restrict__ emb, const float* __restrict__ cs,
                                              unsigned short* __restrict__ en) {
    int gid = blockIdx.x * 256 + threadIdx.x;  // N*64
    float nrm = fmaxf(sqrtf(cs[gid & 63]), 1e-12f);
    en[gid] = f2b(emb[gid] / nrm);
}

__global__ __launch_bounds__(256) void k_sq(const unsigned short* __restrict__ en, float* __restrict__ sqv) {
    int n = blockIdx.x * 256 + threadIdx.x;
    const unsigned short* r = en + (size_t)n * 64;
    float s = 0.f;
#pragma unroll
    for (int q = 0; q < 64; ++q) { float v = b2f(r[q]); s += v * v; }
    sqv[n] = s;
}

// ---------------- fused adjacency via dual-Gram MFMA ----------------
// G = En@En^T, S = Sc@Sc^T (both [N,64] bf16, K=64); out = 1 + tanh(-(sq_i+sq_j-2G)*S)
__global__ __launch_bounds__(256) void k_adj_mfma(const unsigned short* __restrict__ en,
                                                  const unsigned short* __restrict__ sc,
                                                  const float* __restrict__ sqv, float* __restrict__ outp) {
    __shared__ unsigned short Ei[128 * 40], Ej[128 * 40], Si[128 * 40], Sj[128 * 40];
    __shared__ float sqi[128], sqj[128];
    const int tid = threadIdx.x;
    const int i0 = blockIdx.y * 128, j0 = blockIdx.x * 128;
    if (tid < 128) sqi[tid] = sqv[i0 + tid];
    else sqj[tid - 128] = sqv[j0 + tid - 128];
    const int w = tid >> 6, L = tid & 63;
    const int wm = w >> 1, wn = w & 1;
    const int lm = L & 15, koff = (L >> 4) * 8;
    const f32x4 zero = {0.f, 0.f, 0.f, 0.f};
    f32x4 ag[4][4], as_[4][4];
#pragma unroll
    for (int i = 0; i < 4; ++i)
#pragma unroll
        for (int j = 0; j < 4; ++j) { ag[i][j] = zero; as_[i][j] = zero; }

#pragma unroll
    for (int k0 = 0; k0 < 64; k0 += 32) {
#pragma unroll
        for (int it = 0; it < 2; ++it) {
            int f = tid + it * 256;
            int r = f >> 2, q = f & 3;
            *(bf16x8*)&Ei[r * 40 + q * 8] = *(const bf16x8*)(en + (size_t)(i0 + r) * 64 + k0 + q * 8);
            *(bf16x8*)&Ej[r * 40 + q * 8] = *(const bf16x8*)(en + (size_t)(j0 + r) * 64 + k0 + q * 8);
            *(bf16x8*)&Si[r * 40 + q * 8] = *(const bf16x8*)(sc + (size_t)(i0 + r) * 64 + k0 + q * 8);
            *(bf16x8*)&Sj[r * 40 + q * 8] = *(const bf16x8*)(sc + (size_t)(j0 + r) * 64 + k0 + q * 8);
        }
        __syncthreads();
        bf16x8 ae[4], be[4], az[4], bz[4];
#pragma unroll
        for (int i = 0; i < 4; ++i) {
            int row = (wm * 64 + i * 16 + lm) * 40 + koff;
            ae[i] = *(const bf16x8*)&Ei[row];
            az[i] = *(const bf16x8*)&Si[row];
        }
#pragma unroll
        for (int j = 0; j < 4; ++j) {
            int row = (wn * 64 + j * 16 + lm) * 40 + koff;
            be[j] = *(const bf16x8*)&Ej[row];
            bz[j] = *(const bf16x8*)&Sj[row];
        }
#pragma unroll
        for (int i = 0; i < 4; ++i)
#pragma unroll
            for (int j = 0; j < 4; ++j) {
                ag[i][j] = __builtin_amdgcn_mfma_f32_16x16x32_bf16(ae[i], be[j], ag[i][j], 0, 0, 0);
                as_[i][j] = __builtin_amdgcn_mfma_f32_16x16x32_bf16(az[i], bz[j], as_[i][j], 0, 0, 0);
            }
        __syncthreads();
    }

#pragma unroll
    for (int i = 0; i < 4; ++i) {
        int rl = wm * 64 + i * 16 + (L >> 4) * 4;
#pragma unroll
        for (int j = 0; j < 4; ++j) {
            int cl = wn * 64 + j * 16 + lm;
            float sj = sqj[cl];
#pragma unroll
            for (int r = 0; r < 4; ++r) {
                float si = sqi[rl + r];
                float g = ag[i][j][r], s = as_[i][j][r];
                outp[(size_t)(i0 + rl + r) * N + (j0 + cl)] = 1.f + tanhf(-(si + sj - 2.f * g) * s);
            }
        }
    }
}

}  // namespace

extern "C" void kernel_launch(void* const* d_in, const int* in_sizes, int n_in,
                              void* d_out, int out_size, void* d_ws, size_t ws_size,
                              hipStream_t stream) {
    const int* ei = (const int*)d_in[0];
    const float* ew = (const float*)d_in[1];
    const float* feat = (const float*)d_in[2];
    const int* com = (const int*)d_in[3];
    const float* nw = (const float*)d_in[4];
    const float* gat_W = (const float*)d_in[5];
    const float* gat_asrc = (const float*)d_in[6];
    const float* gat_adst = (const float*)d_in[7];
    const float* lstm_Wx = (const float*)d_in[8];
    const float* lstm_Wh = (const float*)d_in[9];
    const float* lstm_b = (const float*)d_in[10];
    const float* emb_W0 = (const float*)d_in[11];
    const float* emb_b0 = (const float*)d_in[12];
    const float* emb_W1 = (const float*)d_in[13];
    const float* emb_b1 = (const float*)d_in[14];
    const float* scal_W0 = (const float*)d_in[15];
    const float* scal_b0 = (const float*)d_in[16];
    const float* scal_W1 = (const float*)d_in[17];
    const float* scal_b1 = (const float*)d_in[18];
    float* out = (float*)d_out;

    char* wp = (char*)d_ws;
    auto alloc = [&](size_t bytes) -> void* {
        void* p = (void*)wp;
        wp += (bytes + 255) & ~(size_t)255;
        return p;
    };
    typedef unsigned short ushort_t;
    int* csr_src = (int*)alloc((size_t)T * E * 4);
    float* csr_wf = (float*)alloc((size_t)T * E * 4);
    int* csr_off = (int*)alloc((size_t)T * (N + 1) * 4);
    int* deg = (int*)alloc((size_t)T * N * 4);
    float* bufA = (float*)alloc((size_t)T * N * DG * 4);      // GAT h (fp32)
    float* bufB = (float*)alloc((size_t)T * N * DG * 4);      // GAT layer-1 output (fp32)
    ushort_t* xb = (ushort_t*)alloc((size_t)T * N * DG * 2);  // bf16 GEMM A operand
    float* ssrc = (float*)alloc((size_t)T * N * H * 4);
    float* sdst = (float*)alloc((size_t)T * N * H * 4);
    float* numb = (float*)alloc((size_t)T * C * DG * 4);
    float* denb = (float*)alloc((size_t)T * C * 4);
    float* macv = (float*)alloc((size_t)T * DG * 4);
    float* alph = (float*)alloc((size_t)T * N * 3 * 4);
    ushort_t* aggb = (ushort_t*)alloc((size_t)T * N * DAGG * 2);
    float* zbuf = (float*)alloc((size_t)N * ZW * 4);
    ushort_t* hb = (ushort_t*)alloc((size_t)N * DR * 2);
    float* cbuf = (float*)alloc((size_t)N * DR * 4);
    ushort_t* e1b = (ushort_t*)alloc((size_t)N * 128 * 2);
    ushort_t* s1b = (ushort_t*)alloc((size_t)N * 128 * 2);
    float* embb = (float*)alloc((size_t)N * 64 * 4);
    ushort_t* sclb = (ushort_t*)alloc((size_t)N * 64 * 2);
    ushort_t* enb = (ushort_t*)alloc((size_t)N * 64 * 2);
    float* cols = (float*)alloc(64 * 4);
    float* sqb = (float*)alloc((size_t)N * 4);
    // transposed bf16 weights
    ushort_t* gWT0 = (ushort_t*)alloc((size_t)128 * 128 * 2);
    ushort_t* gWT1 = (ushort_t*)alloc((size_t)128 * 128 * 2);
    ushort_t* WxT = (ushort_t*)alloc((size_t)1024 * 384 * 2);
    ushort_t* WhT = (ushort_t*)alloc((size_t)1024 * 256 * 2);
    ushort_t* W0T = (ushort_t*)alloc((size_t)128 * 256 * 2);
    ushort_t* W1T = (ushort_t*)alloc((size_t)128 * 128 * 2);
    ushort_t* S0T = (ushort_t*)alloc((size_t)128 * 256 * 2);
    ushort_t* S1T = (ushort_t*)alloc((size_t)128 * 128 * 2);

    // ---- weight prep (every launch; ws is re-poisoned) ----
    k_wtrans<<<dim3(2, 128), 64, 0, stream>>>(gat_W, gWT0, 128, 128);
    k_wtrans<<<dim3(2, 128), 64, 0, stream>>>(gat_W + DG * DG, gWT1, 128, 128);
    k_wtrans<<<dim3(6, 1024), 64, 0, stream>>>(lstm_Wx, WxT, 384, 1024);
    k_wtrans<<<dim3(4, 1024), 64, 0, stream>>>(lstm_Wh, WhT, 256, 1024);
    k_wtrans<<<dim3(4, 128), 64, 0, stream>>>(emb_W0, W0T, 256, 128);
    k_wtrans<<<dim3(2, 128), 64, 0, stream>>>(emb_W1, W1T, 128, 64);
    k_wtrans<<<dim3(4, 128), 64, 0, stream>>>(scal_W0, S0T, 256, 128);
    k_wtrans<<<dim3(2, 128), 64, 0, stream>>>(scal_W1, S1T, 128, 64);

    // ---- CSR by dst (shared by both GAT layers) ----
    hipMemsetAsync(deg, 0, (size_t)T * N * 4, stream);
    k_count<<<(T * E) / 256, 256, 0, stream>>>(ei, deg);
    k_scan<<<T, 256, 0, stream>>>(deg, csr_off);
    hipMemsetAsync(deg, 0, (size_t)T * N * 4, stream);
    k_fill<<<(T * E) / 256, 256, 0, stream>>>(ei, ew, csr_off, deg, csr_src, csr_wf);

    // ---- GAT layer 0: feat(bf16) @ W0 -> h; agg -> xb (bf16) ----
    k_f2bv<<<(T * N * DG) / 256, 256, 0, stream>>>(feat, xb);
    k_mgemm<0, 1, false><<<dim3(1, (T * N) / 128), 256, 0, stream>>>(xb, gWT0, 128, nullptr, nullptr, 0,
                                                                     nullptr, bufA, T * N, 128);
    k_scores<<<(T * N * H) / 256, 256, 0, stream>>>(bufA, gat_asrc, gat_adst, ssrc, sdst);
    k_gat_agg<true><<<dim3(N / 32, T), 256, 0, stream>>>(bufA, ssrc, sdst, csr_src, csr_wf, csr_off, xb);
    // ---- GAT layer 1: xb @ W1 -> h; agg -> bufB (fp32) ----
    k_mgemm<0, 1, false><<<dim3(1, (T * N) / 128), 256, 0, stream>>>(xb, gWT1, 128, nullptr, nullptr, 0,
                                                                     nullptr, bufA, T * N, 128);
    k_scores<<<(T * N * H) / 256, 256, 0, stream>>>(bufA, gat_asrc + H * DH, gat_adst + H * DH, ssrc, sdst);
    k_gat_agg<false><<<dim3(N / 32, T), 256, 0, stream>>>(bufA, ssrc, sdst, csr_src, csr_wf, csr_off, bufB);

    // ---- fuse to aggb [T,N,384] bf16 ----
    hipMemsetAsync(numb, 0, (size_t)T * C * DG * 4, stream);
    hipMemsetAsync(denb, 0, (size_t)T * C * 4, stream);
    k_fuse_scatter<<<(T * N * DG) / 256, 256, 0, stream>>>(bufB, com, nw, numb, denb);
    k_fuse_macro<<<(T * DG + 255) / 256, 256, 0, stream>>>(numb, denb, macv);
    k_fuse_alpha<<<(T * N) / 256, 256, 0, stream>>>(bufB, com, numb, denb, macv, alph);
    k_fuse_agg<<<(T * N * DG) / 256, 256, 0, stream>>>(bufB, com, numb, denb, macv, alph, aggb);

    // ---- LSTM over T steps (dual-K MFMA GEMM + gates) ----
    hipMemsetAsync(hb, 0, (size_t)N * DR * 2, stream);
    hipMemsetAsync(cbuf, 0, (size_t)N * DR * 4, stream);
    for (int t = 0; t < T; ++t) {
        k_mgemm<0, 2, false><<<dim3(ZW / 128, N / 128), 256, 0, stream>>>(
            aggb + (size_t)t * N * DAGG, WxT, 384, hb, WhT, 256, lstm_b, zbuf, N, ZW);
        k_gates<<<(N * DR) / 256, 256, 0, stream>>>(zbuf, cbuf, hb);
    }

    // ---- decoders (MFMA) ----
    k_mgemm<1, 1, true><<<dim3(1, N / 128), 256, 0, stream>>>(hb, W0T, 256, nullptr, nullptr, 0, emb_b0, e1b, N, 128);
    k_mgemm<1, 1, false><<<dim3(1, N / 128), 256, 0, stream>>>(e1b, W1T, 128, nullptr, nullptr, 0, emb_b1, embb, N, 64);
    k_mgemm<2, 1, true><<<dim3(1, N / 128), 256, 0, stream>>>(hb, S0T, 256, nullptr, nullptr, 0, scal_b0, s1b, N, 128);
    k_mgemm<2, 1, true><<<dim3(1, N / 128), 256, 0, stream>>>(s1b, S1T, 128, nullptr, nullptr, 0, scal_b1, sclb, N, 64);

    // emb goes to output tail (fp32)
    hipMemcpyAsync(out + (size_t)N * N, embb, (size_t)N * 64 * 4, hipMemcpyDeviceToDevice, stream);

    // ---- normalize + pairwise adjacency (dual-Gram MFMA) ----
    hipMemsetAsync(cols, 0, 64 * 4, stream);
    k_colsum<<<N / 64, 256, 0, stream>>>(embb, cols);
    k_embn<<<(N * 64) / 256, 256, 0, stream>>>(embb, cols, enb);
    k_sq<<<N / 256, 256, 0, stream>>>(enb, sqb);
    k_adj_mfma<<<dim3(N / 128, N / 128), 256, 0, stream>>>(enb, sclb, sqb, out);
}